// Round 1
// baseline (338.354 us; speedup 1.0000x reference)
//
#include <hip/hip_runtime.h>

// BezierToImageLayer: B=256 samples, L=160 curves, N=30 pts/curve, W=60 image.
// Sparse Gaussian splatting: ALPHA=2e-4 -> sigma ~0.85 px, so each curve point
// only touches an 8x8 pixel window (pixels at distance >=4px contribute
// exp(-22.2) ~ 2e-10; x4800 terms -> ~1e-6 total error vs 2e-2 threshold).

#define WIDTH 60
#define LCURVES 160
#define NSAMP 30
#define INV_ALPHA 5000.0f   // 1/0.0002
#define BLOCK 1024

__global__ __launch_bounds__(BLOCK) void bezier_splat_kernel(
    const float* __restrict__ x, float* __restrict__ out) {
    __shared__ float acc[WIDTH * WIDTH];

    const int tid = threadIdx.x;
    const int b = blockIdx.x;

    // zero the LDS accumulator tile
    for (int i = tid; i < WIDTH * WIDTH; i += BLOCK) acc[i] = 0.0f;
    __syncthreads();

    const float* xb = x + (size_t)b * LCURVES * 8;
    const int total = LCURVES * NSAMP;  // 4800 splats per sample

    for (int idx = tid; idx < total; idx += BLOCK) {
        // l = idx % 160 so consecutive lanes hit DIFFERENT curves ->
        // scatter addresses decorrelated -> fewer LDS atomic collisions
        int l = idx % LCURVES;
        int n = idx / LCURVES;

        // warped Bernstein-like basis (matches reference _bezier_basis)
        float tt = (float)n * (1.0f / NSAMP);
        tt = 2.0f * tt * tt * tt - 3.0f * tt * tt + 2.0f * tt;
        float tb = 1.0f - tt;
        float t2 = tt * tt;
        float w0 = t2 * tt;                       // t^3          -> ctrl 0
        float w1 = 3.0f * (t2 - w0);              // 3(t^2-t^3)   -> ctrl 1
        float w2 = 3.0f * (w0 - 2.0f * t2 + tt);  // 3(t^3-2t^2+t)-> ctrl 2
        float w3 = tb * tb * tb;                  // (1-t)^3      -> ctrl 3

        const float4* c = (const float4*)(xb + l * 8);
        float4 c0 = c[0];  // x0 y0 x1 y1
        float4 c1 = c[1];  // x2 y2 x3 y3
        float X = w0 * c0.x + w1 * c0.z + w2 * c1.x + w3 * c1.z;
        float Y = w0 * c0.y + w1 * c0.w + w2 * c1.y + w3 * c1.w;

        // 8-pixel window centered on the point (covers |dist| < 4 px)
        int i0 = (int)floorf(X * (float)WIDTH) - 3;
        int j0 = (int)floorf(Y * (float)WIDTH) - 3;

        float wx[8], wy[8];
#pragma unroll
        for (int a = 0; a < 8; ++a) {
            float dx = (float)(i0 + a) * (1.0f / WIDTH) - X;
            wx[a] = __expf(-dx * dx * INV_ALPHA);
            float dy = (float)(j0 + a) * (1.0f / WIDTH) - Y;
            wy[a] = __expf(-dy * dy * INV_ALPHA);
        }

#pragma unroll
        for (int a = 0; a < 8; ++a) {
            int i = i0 + a;
            if ((unsigned)i >= WIDTH) continue;
            float wxa = wx[a];
            if (wxa < 1e-9f) continue;  // whole row negligible
            int base = i * WIDTH;
#pragma unroll
            for (int bb = 0; bb < 8; ++bb) {
                int j = j0 + bb;
                float p = wxa * wy[bb];
                // predicate off tiny products: most of the 64-lane exec mask
                // goes inactive -> fewer LDS atomic bank collisions
                if ((unsigned)j < WIDTH && p > 1e-9f) {
                    atomicAdd(&acc[base + j], p);
                }
            }
        }
    }
    __syncthreads();

    // epilogue: clamp and coalesced store
    float* ob = out + (size_t)b * (WIDTH * WIDTH);
    for (int i = tid; i < WIDTH * WIDTH; i += BLOCK) {
        ob[i] = fminf(acc[i], 1.0f);
    }
}

extern "C" void kernel_launch(void* const* d_in, const int* in_sizes, int n_in,
                              void* d_out, int out_size, void* d_ws, size_t ws_size,
                              hipStream_t stream) {
    const float* x = (const float*)d_in[0];
    float* out = (float*)d_out;
    int B = in_sizes[0] / (LCURVES * 8);  // 256
    bezier_splat_kernel<<<B, BLOCK, 0, stream>>>(x, out);
}

// Round 2
// 273.620 us; speedup vs baseline: 1.2366x; 1.2366x over previous
//
#include <hip/hip_runtime.h>

// BezierToImageLayer: B=256, L=160 curves, N=30 pts, W=60 image, alpha=2e-4.
// Sparse Gaussian splatting with a 6x6 tap window (taps floor-2..floor+3 are
// centered on the point; nearest excluded tap is >=3px away ->
// exp(-1.3889*9)=3.7e-6 per dropped term, total error ~2e-3 << 2e-2).
//
// R2 design: branch-free inner loop. LDS accumulator is guard-padded
// (66x66, image at +2,+2) so out-of-image taps land in guard cells with NO
// clamping, NO masks, NO branches -- each product is v_mul + ds_add_f32 with
// a compile-time offset immediate off a single base pointer.

#define WIDTH 60
#define LCURVES 160
#define NSAMP 30
#define BLOCK 1024
#define PS 66                 // padded image stride (guard of 2 low / 3 high)
#define PSZ (PS * PS)         // 4356 floats = 17.4 KB
// exp(-d^2/alpha) = exp2(d^2 * (-1/alpha * log2(e)))
#define NEG_INVA_LOG2E (-7213.4752f)   // -5000 * 1.4426950408889634

__global__ __launch_bounds__(BLOCK) void bezier_splat_kernel(
    const float* __restrict__ x, float* __restrict__ out) {
    __shared__ float acc[PSZ];

    const int tid = threadIdx.x;
    const int b = blockIdx.x;

    for (int i = tid; i < PSZ; i += BLOCK) acc[i] = 0.0f;
    __syncthreads();

    const float* xb = x + (size_t)b * LCURVES * 8;
    const int total = LCURVES * NSAMP;  // 4800 splats

    for (int idx = tid; idx < total; idx += BLOCK) {
        // lane -> distinct curve so scatter addresses are decorrelated
        int l = idx % LCURVES;
        int n = idx / LCURVES;

        // warped Bernstein basis (matches reference _bezier_basis)
        float tt = (float)n * (1.0f / NSAMP);
        tt = 2.0f * tt * tt * tt - 3.0f * tt * tt + 2.0f * tt;
        float tb = 1.0f - tt;
        float t2 = tt * tt;
        float w0 = t2 * tt;
        float w1 = 3.0f * (t2 - w0);
        float w2 = 3.0f * (w0 - 2.0f * t2 + tt);
        float w3 = tb * tb * tb;

        const float4* c = (const float4*)(xb + l * 8);
        float4 c0 = c[0];  // x0 y0 x1 y1
        float4 c1 = c[1];  // x2 y2 x3 y3
        float X = w0 * c0.x + w1 * c0.z + w2 * c1.x + w3 * c1.z;
        float Y = w0 * c0.y + w1 * c0.w + w2 * c1.y + w3 * c1.w;

        // X,Y in [0,1] (convex hull of [0,1]^2 ctrl pts) -> i0,j0 in [0,60]
        float uX = X * (float)WIDTH;
        float uY = Y * (float)WIDTH;
        int i0 = (int)floorf(uX);
        int j0 = (int)floorf(uY);

        // 6 separable tap weights per axis, taps k = a-2, a in [0,6)
        float wx[6], wy[6];
#pragma unroll
        for (int a = 0; a < 6; ++a) {
            float dx = (float)(i0 + a - 2) * (1.0f / WIDTH) - X;
            wx[a] = exp2f(dx * dx * NEG_INVA_LOG2E);
            float dy = (float)(j0 + a - 2) * (1.0f / WIDTH) - Y;
            wy[a] = exp2f(dy * dy * NEG_INVA_LOG2E);
        }

        // base = padded address of tap (a=0,b=0); offsets are compile-time.
        // padded idx = (i0 + (a-2) + 2)*PS + (j0 + (b-2) + 2) = i0*PS+j0 + a*PS+b
        // i0,j0 in [0,60] -> max addr 60*66+60 + 5*66+5 = 4355 < 4356. In range.
        float* p0 = &acc[i0 * PS + j0];
#pragma unroll
        for (int a = 0; a < 6; ++a) {
            float wxa = wx[a];
#pragma unroll
            for (int bb = 0; bb < 6; ++bb) {
                atomicAdd(p0 + (a * PS + bb), wxa * wy[bb]);
            }
        }
    }
    __syncthreads();

    // epilogue: clamp, discard guard cells, coalesced store
    float* ob = out + (size_t)b * (WIDTH * WIDTH);
    for (int i = tid; i < WIDTH * WIDTH; i += BLOCK) {
        int r = i / WIDTH, cidx = i - r * WIDTH;
        ob[i] = fminf(acc[(r + 2) * PS + (cidx + 2)], 1.0f);
    }
}

extern "C" void kernel_launch(void* const* d_in, const int* in_sizes, int n_in,
                              void* d_out, int out_size, void* d_ws, size_t ws_size,
                              hipStream_t stream) {
    const float* x = (const float*)d_in[0];
    float* out = (float*)d_out;
    int B = in_sizes[0] / (LCURVES * 8);  // 256
    bezier_splat_kernel<<<B, BLOCK, 0, stream>>>(x, out);
}

// Round 3
// 78.236 us; speedup vs baseline: 4.3248x; 3.4974x over previous
//
#include <hip/hip_runtime.h>

// BezierToImageLayer as a sparse-fill MFMA GEMM.
// result[b,i,j] = clamp(sum_k gx[k][i]*gy[k][j]) with k = 4800 splats:
// a 64x64x4800 f16 GEMM per sample. Gx/Gy are 6-sparse per column (alpha=2e-4
// -> 6-tap window, same as R2, error ~2e-3 << 2e-2) and built in LDS with
// plain ds_write_b16 (each splat owns its k-column -> NO atomics; R2 showed
// LDS atomics cost ~3cyc/lane = 186 cyc/wave-instr).
//
// Block = 256 thr = 4 waves, one block per sample. Each wave owns a PRIVATE
// 64x64 f16 tile pair (Gx,Gy) and a disjoint quarter of K -> no barriers in
// the main loop. Column index is XOR-swizzled (col = k ^ ((row&7)<<3)) so
// MFMA fragment ds_read_b128 hits the LDS bandwidth floor without padding;
// tiles total exactly 64 KB. K-partials reduced once at the end via LDS reuse.
//
// Tile row r = image row r-2 (A/B matrix row m = image pixel m-2), so C rows
// 2..61 are the 60 output pixels; splat windows reaching image rows 62/63 are
// clamped into tile row 63 (image 61, discarded output).

#define WIDTH 60
#define LCURVES 160
#define NSAMP 30
#define NEG_INVA_LOG2E (-7213.4752f)   // -(1/alpha)*log2(e) = -5000*1.442695

typedef _Float16 half8 __attribute__((ext_vector_type(8)));
typedef float floatx4 __attribute__((ext_vector_type(4)));

__global__ __launch_bounds__(256) void bezier_mfma_kernel(
    const float* __restrict__ x, float* __restrict__ out) {
    // 4 waves x (Gx + Gy) x 64x64 f16 = 65536 B; reused as reduction buffer.
    __shared__ __align__(16) char smem[65536];

    const int tid = threadIdx.x;
    const int lane = tid & 63;
    const int w = tid >> 6;          // wave id 0..3
    const int b = blockIdx.x;
    const int m = lane & 15;         // fragment row/col within 16
    const int q = lane >> 4;         // quad 0..3

    // zero all tiles (4096 float4s)
    float4* sz = (float4*)smem;
#pragma unroll
    for (int i = 0; i < 16; ++i)
        sz[tid + 256 * i] = make_float4(0.f, 0.f, 0.f, 0.f);
    __syncthreads();

    _Float16* gx = (_Float16*)(smem + w * 16384);  // [64 rows][64 cols] swizzled
    _Float16* gy = gx + 4096;

    floatx4 acc[4][4];
#pragma unroll
    for (int ti = 0; ti < 4; ++ti)
#pragma unroll
        for (int tj = 0; tj < 4; ++tj)
            acc[ti][tj] = (floatx4){0.f, 0.f, 0.f, 0.f};

    const float* xb = x + (size_t)b * (LCURVES * 8);
    int prev_i0 = 0, prev_j0 = 0;   // first-iter zeroing hits already-zero cells

    // 75 chunks of 64 splats; wave w takes chunks w, w+4, ... (disjoint K)
    for (int c = w; c < 75; c += 4) {
        int s = c * 64 + lane;            // this lane's splat = its k-column
        int l = s % LCURVES;
        int n = s / LCURVES;

        const float4* cp = (const float4*)(xb + l * 8);
        float4 c0 = cp[0];  // x0 y0 x1 y1
        float4 c1 = cp[1];  // x2 y2 x3 y3

        // warped Bernstein basis (matches reference _bezier_basis)
        float tt = (float)n * (1.0f / NSAMP);
        tt = 2.0f * tt * tt * tt - 3.0f * tt * tt + 2.0f * tt;
        float tb = 1.0f - tt, t2 = tt * tt;
        float w0 = t2 * tt;
        float w1 = 3.0f * (t2 - w0);
        float w2 = 3.0f * tt * tb * tb;
        float w3 = tb * tb * tb;
        float X = w0 * c0.x + w1 * c0.z + w2 * c1.x + w3 * c1.z;
        float Y = w0 * c0.y + w1 * c0.w + w2 * c1.y + w3 * c1.w;

        int i0 = (int)floorf(X * (float)WIDTH);
        int j0 = (int)floorf(Y * (float)WIDTH);
        i0 = min(max(i0, 0), 59);
        j0 = min(max(j0, 0), 59);

        // zero previous chunk's 12 cells (same lane, in-order DS -> safe),
        // then write this chunk's 12 tap weights. No other lane touches
        // column `lane`, so plain stores suffice.
#pragma unroll
        for (int a = 0; a < 6; ++a) {
            int rz = min(prev_i0 + a, 63);
            gx[rz * 64 + (lane ^ ((rz & 7) << 3))] = (_Float16)0;
            int rz2 = min(prev_j0 + a, 63);
            gy[rz2 * 64 + (lane ^ ((rz2 & 7) << 3))] = (_Float16)0;
        }
        float bx = (float)(i0 - 2) * (1.0f / WIDTH) - X;
        float by = (float)(j0 - 2) * (1.0f / WIDTH) - Y;
#pragma unroll
        for (int a = 0; a < 6; ++a) {
            float dx = bx + (float)a * (1.0f / WIDTH);
            float vx = __builtin_amdgcn_exp2f(dx * dx * NEG_INVA_LOG2E);
            int r = min(i0 + a, 63);
            gx[r * 64 + (lane ^ ((r & 7) << 3))] = (_Float16)vx;
            float dy = by + (float)a * (1.0f / WIDTH);
            float vy = __builtin_amdgcn_exp2f(dy * dy * NEG_INVA_LOG2E);
            int r2 = min(j0 + a, 63);
            gy[r2 * 64 + (lane ^ ((r2 & 7) << 3))] = (_Float16)vy;
        }
        prev_i0 = i0;
        prev_j0 = j0;

        // MFMA over this chunk's K=64: A[m][k]=gx(row m)[k], B[k][n]=gy(row n)[k]
        // A-frag: lane(m,q) holds k = kk*32 + q*8 + j ; swizzled col base =
        // 8*((kk*4+q) ^ (row&7)) -> contiguous 16B -> ds_read_b128.
#pragma unroll
        for (int kk = 0; kk < 2; ++kk) {
            half8 af[4], bf[4];
#pragma unroll
            for (int t = 0; t < 4; ++t) {
                int ra = t * 16 + m;
                af[t] = *(const half8*)&gx[ra * 64 + (((kk * 4 + q) ^ (ra & 7)) << 3)];
                bf[t] = *(const half8*)&gy[ra * 64 + (((kk * 4 + q) ^ (ra & 7)) << 3)];
            }
#pragma unroll
            for (int ti = 0; ti < 4; ++ti)
#pragma unroll
                for (int tj = 0; tj < 4; ++tj)
                    acc[ti][tj] = __builtin_amdgcn_mfma_f32_16x16x32_f16(
                        af[ti], bf[tj], acc[ti][tj], 0, 0, 0);
        }
    }

    // Reduce the 4 K-partials. Waves 1..3 park partials in LDS (tile reuse),
    // wave 0 sums + clamps + stores. C/D layout: col=lane&15, row=quad*4+reg.
    __syncthreads();
    if (w > 0) {
        float* red = (float*)smem + (w - 1) * (64 * 65);  // stride 65: no conflicts
#pragma unroll
        for (int ti = 0; ti < 4; ++ti)
#pragma unroll
            for (int tj = 0; tj < 4; ++tj)
#pragma unroll
                for (int r = 0; r < 4; ++r)
                    red[(ti * 16 + q * 4 + r) * 65 + tj * 16 + m] = acc[ti][tj][r];
    }
    __syncthreads();
    if (w == 0) {
        float* r0 = (float*)smem;
        float* r1 = r0 + 64 * 65;
        float* r2 = r1 + 64 * 65;
        float* ob = out + (size_t)b * (WIDTH * WIDTH);
#pragma unroll
        for (int ti = 0; ti < 4; ++ti)
#pragma unroll
            for (int tj = 0; tj < 4; ++tj)
#pragma unroll
                for (int r = 0; r < 4; ++r) {
                    int row = ti * 16 + q * 4 + r;
                    int col = tj * 16 + m;
                    int i = row - 2, j = col - 2;
                    if ((unsigned)i < WIDTH && (unsigned)j < WIDTH) {
                        float v = acc[ti][tj][r] + r0[row * 65 + col] +
                                  r1[row * 65 + col] + r2[row * 65 + col];
                        ob[i * WIDTH + j] = fminf(v, 1.0f);
                    }
                }
    }
}

extern "C" void kernel_launch(void* const* d_in, const int* in_sizes, int n_in,
                              void* d_out, int out_size, void* d_ws, size_t ws_size,
                              hipStream_t stream) {
    const float* x = (const float*)d_in[0];
    float* out = (float*)d_out;
    int B = in_sizes[0] / (LCURVES * 8);  // 256
    bezier_mfma_kernel<<<B, 256, 0, stream>>>(x, out);
}